// Round 7
// baseline (838.092 us; speedup 1.0000x reference)
//
#include <hip/hip_runtime.h>

#define N_NODES 100000
#define N_EDGES 1600000
#define D 64

#define BIN_ROWS 256       // rows per bin; 256x64 f32 acc tile = 64 KB LDS
#define NBINS 391          // ceil(100000 / 256)
#define BIN_CAP 5120       // slots/bin: mean 4096, sigma ~64 -> +16 sigma
#define CHUNK 4096         // edges per pass-A block
#define NCHUNK ((N_EDGES + CHUNK - 1) / CHUNK)   // 391
#define EPT (CHUNK / 256)  // 16 edges per thread

__device__ __forceinline__ unsigned short f2bf(float f) {   // RNE float->bf16
    unsigned int u = __float_as_uint(f);
    u += 0x7FFFu + ((u >> 16) & 1u);
    return (unsigned short)(u >> 16);
}
__device__ __forceinline__ float bf2f(unsigned short u) {
    return __uint_as_float(((unsigned int)u) << 16);
}

// ---------------------------------------------------------------------------
__global__ __launch_bounds__(512) void zero_k(int* __restrict__ bin_cursor) {
    int t = threadIdx.x;
    if (t < NBINS) bin_cursor[t] = 0;
}

// ---- pass A: multisplit edges into 391 bins of 256 rows, coalesced writes -
// record u64: lo32 = (w15<<17)|col ; hi32 = lrow(8b) | (bin<<8)
__global__ __launch_bounds__(256) void passA_k(const int* __restrict__ ei,
                                               const float* __restrict__ ew,
                                               int* __restrict__ bin_cursor,
                                               unsigned long long* __restrict__ binbuf) {
    __shared__ unsigned long long recs[CHUNK];   // 32 KB
    __shared__ int hist[NBINS], start[NBINS], cur[NBINS], gbase[NBINS];
    __shared__ int ts[256];

    int t = threadIdx.x;
    int base = blockIdx.x * CHUNK;
    int cnt = N_EDGES - base; if (cnt > CHUNK) cnt = CHUNK;

    for (int i = t; i < NBINS; i += 256) hist[i] = 0;
    __syncthreads();

    unsigned long long rec[EPT];
    int rbin[EPT];
#pragma unroll
    for (int k = 0; k < EPT; ++k) {
        int j = t + k * 256;
        rbin[k] = -1;
        if (j < cnt) {
            int e = base + j;
            int r = __builtin_nontemporal_load(&ei[e]);
            int c = __builtin_nontemporal_load(&ei[N_EDGES + e]);
            float w = __builtin_nontemporal_load(&ew[e]);
            unsigned int w15 = (unsigned int)__float2int_rn(w * 32767.0f);
            int bin = r >> 8;
            unsigned int lo = (w15 << 17) | (unsigned int)c;
            unsigned int hi = (unsigned int)(r & 255) | ((unsigned int)bin << 8);
            rec[k] = ((unsigned long long)hi << 32) | lo;
            rbin[k] = bin;
            atomicAdd(&hist[bin], 1);
        }
    }
    __syncthreads();

    // exclusive scan over 391 bins: 2 bins per thread + 256-wide Hillis-Steele
    int h0 = (2 * t < NBINS) ? hist[2 * t] : 0;
    int h1 = (2 * t + 1 < NBINS) ? hist[2 * t + 1] : 0;
    int pair = h0 + h1;
    ts[t] = pair;
    __syncthreads();
    for (int off = 1; off < 256; off <<= 1) {
        int v = (t >= off) ? ts[t - off] : 0;
        __syncthreads();
        ts[t] += v;
        __syncthreads();
    }
    int pbase = ts[t] - pair;
    if (2 * t < NBINS) {
        start[2 * t] = pbase; cur[2 * t] = pbase;
        gbase[2 * t] = (h0 > 0) ? atomicAdd(&bin_cursor[2 * t], h0) : 0;
    }
    if (2 * t + 1 < NBINS) {
        start[2 * t + 1] = pbase + h0; cur[2 * t + 1] = pbase + h0;
        gbase[2 * t + 1] = (h1 > 0) ? atomicAdd(&bin_cursor[2 * t + 1], h1) : 0;
    }
    __syncthreads();

    // place into LDS in bin-sorted order
#pragma unroll
    for (int k = 0; k < EPT; ++k) {
        if (rbin[k] >= 0) {
            int p = atomicAdd(&cur[rbin[k]], 1);
            recs[p] = rec[k];
        }
    }
    __syncthreads();

    // coalesced copy-out: consecutive j within a bin -> consecutive global slots
    for (int j = t; j < cnt; j += 256) {
        unsigned long long r = recs[j];
        int bin = (int)(((unsigned int)(r >> 32)) >> 8);
        int gpos = gbase[bin] + (j - start[bin]);
        if (gpos < BIN_CAP)
            __builtin_nontemporal_store(r, &binbuf[(size_t)bin * BIN_CAP + gpos]);
    }
}

// ---- deg: one block per bin -> dinv (LDS u32 atomics, coalesced stream) ---
__global__ __launch_bounds__(256) void deg_k(const int* __restrict__ bin_cursor,
                                             const unsigned long long* __restrict__ binbuf,
                                             float* __restrict__ dinv) {
    __shared__ unsigned int wsum[BIN_ROWS];
    int b = blockIdx.x;
    int t = threadIdx.x;
    int cnt = bin_cursor[b]; if (cnt > BIN_CAP) cnt = BIN_CAP;
    const unsigned long long* bb = binbuf + (size_t)b * BIN_CAP;
    if (t < BIN_ROWS) wsum[t] = 0u;
    __syncthreads();
    for (int j = t; j < cnt; j += 256) {
        unsigned long long r = __builtin_nontemporal_load(&bb[j]);
        int lrow = (int)((unsigned int)(r >> 32) & 255u);
        unsigned int w15 = (((unsigned int)r) >> 17) & 0x7FFFu;
        atomicAdd(&wsum[lrow], w15);
    }
    __syncthreads();
    int n = b * BIN_ROWS + t;
    if (t < BIN_ROWS && n < N_NODES)
        dinv[n] = rsqrtf(1.0f + (float)wsum[t] * (1.0f / 32767.0f));
}

// ---------------------- y' = dinv .* (X * W^T), stored bf16 ---------------
__global__ __launch_bounds__(256) void xw_k(const float* __restrict__ x,
                                            const float* __restrict__ W,
                                            const float* __restrict__ dinv,
                                            unsigned short* __restrict__ yp) {
    __shared__ float xsT[64][68];   // [k][node]
    __shared__ float Wt[64][68];    // [k][feat]
    int tid = threadIdx.x;
    int nbase = blockIdx.x * 64;
#pragma unroll
    for (int r = 0; r < 4; ++r) {   // W: [j][k] row-major, 4096 floats
        int idx = r * 1024 + tid * 4;
        int j = idx >> 6, k = idx & 63;
        float4 v = *(const float4*)(W + idx);
        Wt[k + 0][j] = v.x; Wt[k + 1][j] = v.y; Wt[k + 2][j] = v.z; Wt[k + 3][j] = v.w;
    }
#pragma unroll
    for (int r = 0; r < 4; ++r) {   // x block, transposed into LDS
        int idx = r * 1024 + tid * 4;
        int nl = idx >> 6, k = idx & 63;
        int n = nbase + nl;
        float4 v = (n < N_NODES) ? *(const float4*)(x + n * 64 + k)
                                 : make_float4(0.f, 0.f, 0.f, 0.f);
        xsT[k + 0][nl] = v.x; xsT[k + 1][nl] = v.y; xsT[k + 2][nl] = v.z; xsT[k + 3][nl] = v.w;
    }
    __syncthreads();

    int tx = tid & 15;          // feature group: j0 = tx*4
    int ty = tid >> 4;          // node group:    n0 = ty*4
    float acc[4][4];
#pragma unroll
    for (int i = 0; i < 4; ++i)
#pragma unroll
        for (int j = 0; j < 4; ++j) acc[i][j] = 0.f;

#pragma unroll 8
    for (int k = 0; k < 64; ++k) {
        float4 a = *(const float4*)&xsT[k][ty * 4];
        float4 w = *(const float4*)&Wt[k][tx * 4];
        float av[4] = {a.x, a.y, a.z, a.w};
        float wv[4] = {w.x, w.y, w.z, w.w};
#pragma unroll
        for (int i = 0; i < 4; ++i)
#pragma unroll
            for (int j = 0; j < 4; ++j) acc[i][j] += av[i] * wv[j];
    }
#pragma unroll
    for (int i = 0; i < 4; ++i) {
        int n = nbase + ty * 4 + i;
        if (n < N_NODES) {
            float di = dinv[n];
            ushort4 v;
            v.x = f2bf(di * acc[i][0]);
            v.y = f2bf(di * acc[i][1]);
            v.z = f2bf(di * acc[i][2]);
            v.w = f2bf(di * acc[i][3]);
            *(ushort4*)(yp + n * 64 + tx * 4) = v;   // 8B store
        }
    }
}

// ---- agg: one block per bin; 64 KB LDS acc tile; ds_add_f32 per record ----
// out[n] = dinv[n]*(Σ w·y'[col] + y'[n]) + b     (y' carries dinv factor)
__global__ __launch_bounds__(256) void agg_k(const int* __restrict__ bin_cursor,
                                             const unsigned long long* __restrict__ binbuf,
                                             const float* __restrict__ dinv,
                                             const unsigned short* __restrict__ yp,
                                             const float* __restrict__ b,
                                             float* __restrict__ out) {
    __shared__ float acc[BIN_ROWS * 64];   // exactly 64 KB
    int bin = blockIdx.x;
    int t = threadIdx.x;
    int wv = t >> 6;       // wave 0..3
    int ln = t & 63;       // feature lane
    int cnt = bin_cursor[bin]; if (cnt > BIN_CAP) cnt = BIN_CAP;
    const unsigned long long* bb = binbuf + (size_t)bin * BIN_CAP;

#pragma unroll
    for (int k = 0; k < 64; ++k) acc[t + k * 256] = 0.0f;
    __syncthreads();

    // each wave streams records strided; all loads independent -> deep MLP
    for (int j = wv * 4; j < cnt; j += 16) {
        if (j + 3 < cnt) {
            unsigned long long r0 = __builtin_nontemporal_load(&bb[j]);
            unsigned long long r1 = __builtin_nontemporal_load(&bb[j + 1]);
            unsigned long long r2 = __builtin_nontemporal_load(&bb[j + 2]);
            unsigned long long r3 = __builtin_nontemporal_load(&bb[j + 3]);
            unsigned int lo0 = (unsigned int)r0, lo1 = (unsigned int)r1;
            unsigned int lo2 = (unsigned int)r2, lo3 = (unsigned int)r3;
            float y0 = bf2f(yp[(lo0 & 0x1FFFFu) * 64 + ln]);
            float y1 = bf2f(yp[(lo1 & 0x1FFFFu) * 64 + ln]);
            float y2 = bf2f(yp[(lo2 & 0x1FFFFu) * 64 + ln]);
            float y3 = bf2f(yp[(lo3 & 0x1FFFFu) * 64 + ln]);
            int lr0 = (int)((unsigned int)(r0 >> 32) & 255u);
            int lr1 = (int)((unsigned int)(r1 >> 32) & 255u);
            int lr2 = (int)((unsigned int)(r2 >> 32) & 255u);
            int lr3 = (int)((unsigned int)(r3 >> 32) & 255u);
            atomicAdd(&acc[lr0 * 64 + ln], (float)(lo0 >> 17) * (1.0f / 32767.0f) * y0);
            atomicAdd(&acc[lr1 * 64 + ln], (float)(lo1 >> 17) * (1.0f / 32767.0f) * y1);
            atomicAdd(&acc[lr2 * 64 + ln], (float)(lo2 >> 17) * (1.0f / 32767.0f) * y2);
            atomicAdd(&acc[lr3 * 64 + ln], (float)(lo3 >> 17) * (1.0f / 32767.0f) * y3);
        } else {
            for (int jj = j; jj < cnt; ++jj) {
                unsigned long long r = __builtin_nontemporal_load(&bb[jj]);
                unsigned int lo = (unsigned int)r;
                float yv = bf2f(yp[(lo & 0x1FFFFu) * 64 + ln]);
                int lr = (int)((unsigned int)(r >> 32) & 255u);
                atomicAdd(&acc[lr * 64 + ln], (float)(lo >> 17) * (1.0f / 32767.0f) * yv);
            }
        }
    }
    __syncthreads();

    // epilogue: fully coalesced
    int nbase = bin * BIN_ROWS;
    float bv = b[ln];
#pragma unroll
    for (int k = 0; k < 64; ++k) {
        int idx = t + k * 256;            // 0..16383
        int lr = idx >> 6;
        int n = nbase + lr;
        if (n < N_NODES) {
            float self = bf2f(yp[(size_t)nbase * 64 + idx]);
            float o = dinv[n] * (acc[idx] + self) + bv;
            __builtin_nontemporal_store(o, &out[(size_t)nbase * 64 + idx]);
        }
    }
}

// ---------------------------------------------------------------------------
extern "C" void kernel_launch(void* const* d_in, const int* in_sizes, int n_in,
                              void* d_out, int out_size, void* d_ws, size_t ws_size,
                              hipStream_t stream) {
    const float* x  = (const float*)d_in[0];
    const int*   ei = (const int*)d_in[1];     // [2, E]
    const float* ew = (const float*)d_in[2];
    const float* W  = (const float*)d_in[3];
    const float* b  = (const float*)d_in[4];
    float* out = (float*)d_out;

    char* ws = (char*)d_ws;
    int*                bin_cursor = (int*)                ws;               // 1.6 KB
    float*              dinv       = (float*)             (ws + 4096);       // 400 KB
    unsigned short*     yp         = (unsigned short*)    (ws + 524288);     // 12.8 MB
    unsigned long long* binbuf     = (unsigned long long*)(ws + 13631488);   // 16.0 MB (end ~29.6 MB)

    zero_k  <<<1, 512, 0, stream>>>(bin_cursor);
    passA_k <<<NCHUNK, 256, 0, stream>>>(ei, ew, bin_cursor, binbuf);
    deg_k   <<<NBINS, 256, 0, stream>>>(bin_cursor, binbuf, dinv);
    xw_k    <<<(N_NODES + 63) / 64, 256, 0, stream>>>(x, W, dinv, yp);
    agg_k   <<<NBINS, 256, 0, stream>>>(bin_cursor, binbuf, dinv, yp, b, out);
}

// Round 8
// 837.549 us; speedup vs baseline: 1.0006x; 1.0006x over previous
//
#include <hip/hip_runtime.h>

#define N_NODES 100000
#define N_EDGES 1600000
#define D 64

#define BIN_ROWS 128       // rows per bin; 128x64 f32 acc tile = 32 KB LDS
#define NBINS 782          // ceil(100000 / 128)
#define BIN_CAP 2560       // slots/bin: mean 2046, sigma ~45 -> +11 sigma
#define CHUNK 4096         // edges per pass-A block
#define NCHUNK ((N_EDGES + CHUNK - 1) / CHUNK)   // 391
#define EPT (CHUNK / 256)  // 16 edges per thread

__device__ __forceinline__ unsigned short f2bf(float f) {   // RNE float->bf16
    unsigned int u = __float_as_uint(f);
    u += 0x7FFFu + ((u >> 16) & 1u);
    return (unsigned short)(u >> 16);
}
__device__ __forceinline__ float bf2f(unsigned short u) {
    return __uint_as_float(((unsigned int)u) << 16);
}

// ---------------------------------------------------------------------------
__global__ __launch_bounds__(1024) void zero_k(int* __restrict__ bin_cursor) {
    int t = threadIdx.x;
    if (t < NBINS) bin_cursor[t] = 0;
}

// ---- pass A: multisplit edges into 782 bins of 128 rows, coalesced writes -
// record u64: lo32 = (w15<<17)|col ; hi32 = lrow(7b) | (bin<<7)
__global__ __launch_bounds__(256) void passA_k(const int* __restrict__ ei,
                                               const float* __restrict__ ew,
                                               int* __restrict__ bin_cursor,
                                               unsigned long long* __restrict__ binbuf) {
    __shared__ unsigned long long recs[CHUNK];   // 32 KB
    __shared__ int hist[NBINS], start[NBINS], cur[NBINS], gbase[NBINS];  // 12.5 KB
    __shared__ int ts[256];

    int t = threadIdx.x;
    int base = blockIdx.x * CHUNK;
    int cnt = N_EDGES - base; if (cnt > CHUNK) cnt = CHUNK;

    for (int i = t; i < NBINS; i += 256) hist[i] = 0;
    __syncthreads();

    unsigned long long rec[EPT];
    int rbin[EPT];
#pragma unroll
    for (int k = 0; k < EPT; ++k) {
        int j = t + k * 256;
        rbin[k] = -1;
        if (j < cnt) {
            int e = base + j;
            int r = __builtin_nontemporal_load(&ei[e]);
            int c = __builtin_nontemporal_load(&ei[N_EDGES + e]);
            float w = __builtin_nontemporal_load(&ew[e]);
            unsigned int w15 = (unsigned int)__float2int_rn(w * 32767.0f);
            int bin = r >> 7;
            unsigned int lo = (w15 << 17) | (unsigned int)c;
            unsigned int hi = (unsigned int)(r & 127) | ((unsigned int)bin << 7);
            rec[k] = ((unsigned long long)hi << 32) | lo;
            rbin[k] = bin;
            atomicAdd(&hist[bin], 1);
        }
    }
    __syncthreads();

    // exclusive scan over 782 bins: 4 bins/thread + 256-wide Hillis-Steele
    int h[4]; int local = 0;
#pragma unroll
    for (int q = 0; q < 4; ++q) {
        int idx = t * 4 + q;
        h[q] = (idx < NBINS) ? hist[idx] : 0;
        local += h[q];
    }
    ts[t] = local;
    __syncthreads();
    for (int off = 1; off < 256; off <<= 1) {
        int v = (t >= off) ? ts[t - off] : 0;
        __syncthreads();
        ts[t] += v;
        __syncthreads();
    }
    int run = ts[t] - local;
#pragma unroll
    for (int q = 0; q < 4; ++q) {
        int idx = t * 4 + q;
        if (idx < NBINS) {
            start[idx] = run; cur[idx] = run;
            gbase[idx] = (h[q] > 0) ? atomicAdd(&bin_cursor[idx], h[q]) : 0;
            run += h[q];
        }
    }
    __syncthreads();

    // place into LDS in bin-sorted order
#pragma unroll
    for (int k = 0; k < EPT; ++k) {
        if (rbin[k] >= 0) {
            int p = atomicAdd(&cur[rbin[k]], 1);
            recs[p] = rec[k];
        }
    }
    __syncthreads();

    // coalesced copy-out: consecutive j within a bin -> consecutive global slots
    for (int j = t; j < cnt; j += 256) {
        unsigned long long r = recs[j];
        int bin = (int)(((unsigned int)(r >> 32)) >> 7);
        int gpos = gbase[bin] + (j - start[bin]);
        if (gpos < BIN_CAP)
            __builtin_nontemporal_store(r, &binbuf[(size_t)bin * BIN_CAP + gpos]);
    }
}

// ---- deg: one block per bin -> dinv (LDS u32 atomics, coalesced stream) ---
__global__ __launch_bounds__(256) void deg_k(const int* __restrict__ bin_cursor,
                                             const unsigned long long* __restrict__ binbuf,
                                             float* __restrict__ dinv) {
    __shared__ unsigned int wsum[BIN_ROWS];
    int b = blockIdx.x;
    int t = threadIdx.x;
    int cnt = bin_cursor[b]; if (cnt > BIN_CAP) cnt = BIN_CAP;
    const unsigned long long* bb = binbuf + (size_t)b * BIN_CAP;
    if (t < BIN_ROWS) wsum[t] = 0u;
    __syncthreads();
    for (int j = t; j < cnt; j += 256) {
        unsigned long long r = __builtin_nontemporal_load(&bb[j]);
        int lrow = (int)((unsigned int)(r >> 32) & 127u);
        unsigned int w15 = (((unsigned int)r) >> 17) & 0x7FFFu;
        atomicAdd(&wsum[lrow], w15);
    }
    __syncthreads();
    int n = b * BIN_ROWS + t;
    if (t < BIN_ROWS && n < N_NODES)
        dinv[n] = rsqrtf(1.0f + (float)wsum[t] * (1.0f / 32767.0f));
}

// ---------------------- y' = dinv .* (X * W^T), stored bf16 ---------------
__global__ __launch_bounds__(256) void xw_k(const float* __restrict__ x,
                                            const float* __restrict__ W,
                                            const float* __restrict__ dinv,
                                            unsigned short* __restrict__ yp) {
    __shared__ float xsT[64][68];   // [k][node]
    __shared__ float Wt[64][68];    // [k][feat]
    int tid = threadIdx.x;
    int nbase = blockIdx.x * 64;
#pragma unroll
    for (int r = 0; r < 4; ++r) {   // W: [j][k] row-major, 4096 floats
        int idx = r * 1024 + tid * 4;
        int j = idx >> 6, k = idx & 63;
        float4 v = *(const float4*)(W + idx);
        Wt[k + 0][j] = v.x; Wt[k + 1][j] = v.y; Wt[k + 2][j] = v.z; Wt[k + 3][j] = v.w;
    }
#pragma unroll
    for (int r = 0; r < 4; ++r) {   // x block, transposed into LDS
        int idx = r * 1024 + tid * 4;
        int nl = idx >> 6, k = idx & 63;
        int n = nbase + nl;
        float4 v = (n < N_NODES) ? *(const float4*)(x + n * 64 + k)
                                 : make_float4(0.f, 0.f, 0.f, 0.f);
        xsT[k + 0][nl] = v.x; xsT[k + 1][nl] = v.y; xsT[k + 2][nl] = v.z; xsT[k + 3][nl] = v.w;
    }
    __syncthreads();

    int tx = tid & 15;          // feature group: j0 = tx*4
    int ty = tid >> 4;          // node group:    n0 = ty*4
    float acc[4][4];
#pragma unroll
    for (int i = 0; i < 4; ++i)
#pragma unroll
        for (int j = 0; j < 4; ++j) acc[i][j] = 0.f;

#pragma unroll 8
    for (int k = 0; k < 64; ++k) {
        float4 a = *(const float4*)&xsT[k][ty * 4];
        float4 w = *(const float4*)&Wt[k][tx * 4];
        float av[4] = {a.x, a.y, a.z, a.w};
        float wv[4] = {w.x, w.y, w.z, w.w};
#pragma unroll
        for (int i = 0; i < 4; ++i)
#pragma unroll
            for (int j = 0; j < 4; ++j) acc[i][j] += av[i] * wv[j];
    }
#pragma unroll
    for (int i = 0; i < 4; ++i) {
        int n = nbase + ty * 4 + i;
        if (n < N_NODES) {
            float di = dinv[n];
            ushort4 v;
            v.x = f2bf(di * acc[i][0]);
            v.y = f2bf(di * acc[i][1]);
            v.z = f2bf(di * acc[i][2]);
            v.w = f2bf(di * acc[i][3]);
            *(ushort4*)(yp + n * 64 + tx * 4) = v;   // 8B store
        }
    }
}

// ---- agg: one block per bin; 32 KB LDS acc; 8 waves, unroll-8 streams -----
// out[n] = dinv[n]*(Σ w·y'[col] + y'[n]) + b     (y' carries dinv factor)
__global__ __launch_bounds__(512) void agg_k(const int* __restrict__ bin_cursor,
                                             const unsigned long long* __restrict__ binbuf,
                                             const float* __restrict__ dinv,
                                             const unsigned short* __restrict__ yp,
                                             const float* __restrict__ b,
                                             float* __restrict__ out) {
    __shared__ float acc[BIN_ROWS * 64];   // 32 KB
    int bin = blockIdx.x;
    int t = threadIdx.x;
    int wv = t >> 6;       // wave 0..7
    int ln = t & 63;       // feature lane
    int cnt = bin_cursor[bin]; if (cnt > BIN_CAP) cnt = BIN_CAP;
    const unsigned long long* bb = binbuf + (size_t)bin * BIN_CAP;

    for (int k = t; k < BIN_ROWS * 64; k += 512) acc[k] = 0.0f;
    __syncthreads();

    // wave-strided stripes of 8: 8 indep record loads, then 8 indep yp loads
    int j = wv * 8;
    for (; j + 7 < cnt; j += 64) {
        unsigned long long r[8];
#pragma unroll
        for (int q = 0; q < 8; ++q)
            r[q] = __builtin_nontemporal_load(&bb[j + q]);
        float yv[8], w[8]; int lr[8];
#pragma unroll
        for (int q = 0; q < 8; ++q) {
            unsigned int lo = (unsigned int)r[q];
            yv[q] = bf2f(yp[(lo & 0x1FFFFu) * 64 + ln]);
            w[q]  = (float)(lo >> 17) * (1.0f / 32767.0f);
            lr[q] = (int)((unsigned int)(r[q] >> 32) & 127u);
        }
#pragma unroll
        for (int q = 0; q < 8; ++q)
            atomicAdd(&acc[lr[q] * 64 + ln], w[q] * yv[q]);
    }
    for (; j < cnt; ++j) {       // partial final stripe of this wave only
        unsigned long long r = __builtin_nontemporal_load(&bb[j]);
        unsigned int lo = (unsigned int)r;
        float yv = bf2f(yp[(lo & 0x1FFFFu) * 64 + ln]);
        int lr = (int)((unsigned int)(r >> 32) & 127u);
        atomicAdd(&acc[lr * 64 + ln], (float)(lo >> 17) * (1.0f / 32767.0f) * yv);
    }
    __syncthreads();

    // epilogue: fully coalesced
    int nbase = bin * BIN_ROWS;
    for (int k = t; k < BIN_ROWS * 64; k += 512) {
        int lr = k >> 6;
        int n = nbase + lr;
        if (n < N_NODES) {
            float self = bf2f(yp[(size_t)nbase * 64 + k]);
            float o = dinv[n] * (acc[k] + self) + b[k & 63];
            __builtin_nontemporal_store(o, &out[(size_t)nbase * 64 + k]);
        }
    }
}

// ---------------------------------------------------------------------------
extern "C" void kernel_launch(void* const* d_in, const int* in_sizes, int n_in,
                              void* d_out, int out_size, void* d_ws, size_t ws_size,
                              hipStream_t stream) {
    const float* x  = (const float*)d_in[0];
    const int*   ei = (const int*)d_in[1];     // [2, E]
    const float* ew = (const float*)d_in[2];
    const float* W  = (const float*)d_in[3];
    const float* b  = (const float*)d_in[4];
    float* out = (float*)d_out;

    char* ws = (char*)d_ws;
    int*                bin_cursor = (int*)                ws;               // 3.1 KB
    float*              dinv       = (float*)             (ws + 4096);       // 400 KB
    unsigned short*     yp         = (unsigned short*)    (ws + 524288);     // 12.8 MB
    unsigned long long* binbuf     = (unsigned long long*)(ws + 13631488);   // 16.0 MB (end ~29.6 MB)

    zero_k  <<<1, 1024, 0, stream>>>(bin_cursor);
    passA_k <<<NCHUNK, 256, 0, stream>>>(ei, ew, bin_cursor, binbuf);
    deg_k   <<<NBINS, 256, 0, stream>>>(bin_cursor, binbuf, dinv);
    xw_k    <<<(N_NODES + 63) / 64, 256, 0, stream>>>(x, W, dinv, yp);
    agg_k   <<<NBINS, 512, 0, stream>>>(bin_cursor, binbuf, dinv, yp, b, out);
}

// Round 9
// 193.117 us; speedup vs baseline: 4.3398x; 4.3370x over previous
//
#include <hip/hip_runtime.h>

#define N_NODES 100000
#define N_EDGES 1600000
#define D 64

#define BIN_ROWS 128       // rows per bin
#define NBINS 782          // ceil(100000 / 128)
#define BIN_CAP 2560       // mean 2046, sigma ~45 -> +11 sigma
#define CHUNK 4096         // edges per pass-A block
#define NCHUNK ((N_EDGES + CHUNK - 1) / CHUNK)   // 391
#define APT (CHUNK / 512)  // 8 edges per thread in passA

__device__ __forceinline__ unsigned short f2bf(float f) {   // RNE float->bf16
    unsigned int u = __float_as_uint(f);
    u += 0x7FFFu + ((u >> 16) & 1u);
    return (unsigned short)(u >> 16);
}
__device__ __forceinline__ float bf2f(unsigned short u) {
    return __uint_as_float(((unsigned int)u) << 16);
}

// ---- pass A: multisplit edges into 782 bins of 128 rows, coalesced writes -
// record u64: lo32 = (w15<<17)|col ; hi32 = lrow(7b) | (bin<<7)
__global__ __launch_bounds__(512) void passA_k(const int* __restrict__ ei,
                                               const float* __restrict__ ew,
                                               int* __restrict__ bin_cursor,
                                               unsigned long long* __restrict__ binbuf) {
    __shared__ unsigned long long recs[CHUNK];   // 32 KB
    __shared__ int hist[NBINS], start[NBINS], gbase[NBINS];   // 9.4 KB
    __shared__ int ts[512];

    int t = threadIdx.x;
    int base = blockIdx.x * CHUNK;
    int cnt = N_EDGES - base; if (cnt > CHUNK) cnt = CHUNK;

    for (int i = t; i < NBINS; i += 512) hist[i] = 0;
    __syncthreads();

    unsigned long long rec[APT];
    int rbin[APT], rank[APT];
#pragma unroll
    for (int k = 0; k < APT; ++k) {
        int j = t + k * 512;
        rbin[k] = -1;
        if (j < cnt) {
            int e = base + j;
            int r = __builtin_nontemporal_load(&ei[e]);
            int c = __builtin_nontemporal_load(&ei[N_EDGES + e]);
            float w = __builtin_nontemporal_load(&ew[e]);
            unsigned int w15 = (unsigned int)__float2int_rn(w * 32767.0f);
            int bin = r >> 7;
            unsigned int lo = (w15 << 17) | (unsigned int)c;
            unsigned int hi = (unsigned int)(r & 127) | ((unsigned int)bin << 7);
            rec[k] = ((unsigned long long)hi << 32) | lo;
            rbin[k] = bin;
            rank[k] = atomicAdd(&hist[bin], 1);   // rank doubles as placement
        }
    }
    __syncthreads();

    // exclusive scan over 782 bins: 2 bins/thread + 512-wide Hillis-Steele
    int idx0 = 2 * t, idx1 = 2 * t + 1;
    int h0 = (idx0 < NBINS) ? hist[idx0] : 0;
    int h1 = (idx1 < NBINS) ? hist[idx1] : 0;
    int pair = h0 + h1;
    ts[t] = pair;
    __syncthreads();
    for (int off = 1; off < 512; off <<= 1) {
        int v = (t >= off) ? ts[t - off] : 0;
        __syncthreads();
        ts[t] += v;
        __syncthreads();
    }
    int pbase = ts[t] - pair;
    if (idx0 < NBINS) {
        start[idx0] = pbase;
        gbase[idx0] = (h0 > 0) ? atomicAdd(&bin_cursor[idx0], h0) : 0;
    }
    if (idx1 < NBINS) {
        start[idx1] = pbase + h0;
        gbase[idx1] = (h1 > 0) ? atomicAdd(&bin_cursor[idx1], h1) : 0;
    }
    __syncthreads();

    // place into LDS bin-sorted using rank (no second atomic)
#pragma unroll
    for (int k = 0; k < APT; ++k)
        if (rbin[k] >= 0)
            recs[start[rbin[k]] + rank[k]] = rec[k];
    __syncthreads();

    // coalesced copy-out (binbuf is re-read by passB: keep cacheable)
    for (int j = t; j < cnt; j += 512) {
        unsigned long long r = recs[j];
        int bin = (int)(((unsigned int)(r >> 32)) >> 7);
        int gpos = gbase[bin] + (j - start[bin]);
        if (gpos < BIN_CAP)
            binbuf[(size_t)bin * BIN_CAP + gpos] = r;
    }
}

// ---- scan bin counts -> global bin bases --------------------------------
__global__ __launch_bounds__(256) void base_k(const int* __restrict__ bin_cursor,
                                              int* __restrict__ bin_base,
                                              int* __restrict__ row_ptr) {
    __shared__ int ts[256];
    int t = threadIdx.x;
    int h[4]; int local = 0;
#pragma unroll
    for (int q = 0; q < 4; ++q) {
        int idx = t * 4 + q;
        int c = (idx < NBINS) ? bin_cursor[idx] : 0;
        if (c > BIN_CAP) c = BIN_CAP;
        h[q] = c; local += c;
    }
    ts[t] = local;
    __syncthreads();
    for (int off = 1; off < 256; off <<= 1) {
        int v = (t >= off) ? ts[t - off] : 0;
        __syncthreads();
        ts[t] += v;
        __syncthreads();
    }
    int run = ts[t] - local;
#pragma unroll
    for (int q = 0; q < 4; ++q) {
        int idx = t * 4 + q;
        if (idx < NBINS) { bin_base[idx] = run; run += h[q]; }
    }
    if (t == 255) row_ptr[N_NODES] = run;
}

// ---- pass B: one block per 128-row bin; LDS-staged row sort; CSR + dinv ---
__global__ __launch_bounds__(256) void passB_k(const int* __restrict__ bin_cursor,
                                               const int* __restrict__ bin_base,
                                               const unsigned long long* __restrict__ binbuf,
                                               unsigned int* __restrict__ csr,
                                               int* __restrict__ row_ptr,
                                               float* __restrict__ dinv) {
    __shared__ unsigned long long stage[BIN_CAP];   // 20 KB
    __shared__ unsigned int outbuf[BIN_CAP];        // 10 KB
    __shared__ int hist[BIN_ROWS], rcur[BIN_ROWS];
    __shared__ unsigned int wsum[BIN_ROWS];
    __shared__ int ts[256];

    int b = blockIdx.x;
    int t = threadIdx.x;
    int cnt = bin_cursor[b]; if (cnt > BIN_CAP) cnt = BIN_CAP;
    const unsigned long long* bb = binbuf + (size_t)b * BIN_CAP;
    int gb = bin_base[b];

    if (t < BIN_ROWS) { hist[t] = 0; wsum[t] = 0u; }
    __syncthreads();

    // single global pass: stage in LDS + histogram + weight sums
    for (int j = t; j < cnt; j += 256) {
        unsigned long long r = bb[j];
        stage[j] = r;
        int lrow = (int)((unsigned int)(r >> 32) & 127u);
        atomicAdd(&hist[lrow], 1);
        atomicAdd(&wsum[lrow], (((unsigned int)r) >> 17) & 0x7FFFu);
    }
    __syncthreads();

    // exclusive scan of 128 row counts (threads 0..127)
    int own = (t < BIN_ROWS) ? hist[t] : 0;
    ts[t] = own;
    __syncthreads();
    for (int off = 1; off < BIN_ROWS; off <<= 1) {
        int v = (t >= off && t < BIN_ROWS) ? ts[t - off] : 0;
        __syncthreads();
        if (t < BIN_ROWS) ts[t] += v;
        __syncthreads();
    }
    if (t < BIN_ROWS) {
        int rs = ts[t] - own;
        rcur[t] = rs;
        int n = b * BIN_ROWS + t;
        if (n < N_NODES) {
            row_ptr[n] = gb + rs;
            dinv[n] = rsqrtf(1.0f + (float)wsum[t] * (1.0f / 32767.0f));
        }
    }
    __syncthreads();

    // reorder row-sorted within LDS
    for (int j = t; j < cnt; j += 256) {
        unsigned long long r = stage[j];
        int lrow = (int)((unsigned int)(r >> 32) & 127u);
        int p = atomicAdd(&rcur[lrow], 1);
        outbuf[p] = (unsigned int)r;    // 4B record: (w15<<17)|col
    }
    __syncthreads();

    // coalesced copy-out
    for (int j = t; j < cnt; j += 256)
        csr[gb + j] = outbuf[j];
}

// ---------------------- y' = dinv .* (X * W^T), stored bf16 ---------------
__global__ __launch_bounds__(256) void xw_k(const float* __restrict__ x,
                                            const float* __restrict__ W,
                                            const float* __restrict__ dinv,
                                            unsigned short* __restrict__ yp) {
    __shared__ float xsT[64][68];   // [k][node]
    __shared__ float Wt[64][68];    // [k][feat]
    int tid = threadIdx.x;
    int nbase = blockIdx.x * 64;
#pragma unroll
    for (int r = 0; r < 4; ++r) {   // W: [j][k] row-major, 4096 floats
        int idx = r * 1024 + tid * 4;
        int j = idx >> 6, k = idx & 63;
        float4 v = *(const float4*)(W + idx);
        Wt[k + 0][j] = v.x; Wt[k + 1][j] = v.y; Wt[k + 2][j] = v.z; Wt[k + 3][j] = v.w;
    }
#pragma unroll
    for (int r = 0; r < 4; ++r) {   // x block, transposed into LDS
        int idx = r * 1024 + tid * 4;
        int nl = idx >> 6, k = idx & 63;
        int n = nbase + nl;
        float4 v = (n < N_NODES) ? *(const float4*)(x + n * 64 + k)
                                 : make_float4(0.f, 0.f, 0.f, 0.f);
        xsT[k + 0][nl] = v.x; xsT[k + 1][nl] = v.y; xsT[k + 2][nl] = v.z; xsT[k + 3][nl] = v.w;
    }
    __syncthreads();

    int tx = tid & 15;          // feature group: j0 = tx*4
    int ty = tid >> 4;          // node group:    n0 = ty*4
    float acc[4][4];
#pragma unroll
    for (int i = 0; i < 4; ++i)
#pragma unroll
        for (int j = 0; j < 4; ++j) acc[i][j] = 0.f;

#pragma unroll 8
    for (int k = 0; k < 64; ++k) {
        float4 a = *(const float4*)&xsT[k][ty * 4];
        float4 w = *(const float4*)&Wt[k][tx * 4];
        float av[4] = {a.x, a.y, a.z, a.w};
        float wv[4] = {w.x, w.y, w.z, w.w};
#pragma unroll
        for (int i = 0; i < 4; ++i)
#pragma unroll
            for (int j = 0; j < 4; ++j) acc[i][j] += av[i] * wv[j];
    }
#pragma unroll
    for (int i = 0; i < 4; ++i) {
        int n = nbase + ty * 4 + i;
        if (n < N_NODES) {
            float di = dinv[n];
            ushort4 v;
            v.x = f2bf(di * acc[i][0]);
            v.y = f2bf(di * acc[i][1]);
            v.z = f2bf(di * acc[i][2]);
            v.w = f2bf(di * acc[i][3]);
            *(ushort4*)(yp + n * 64 + tx * 4) = v;   // 8B store
        }
    }
}

// ---- gather: 1 wave per row; wave-cooperative CSR fetch + readlane --------
// out = dinv[r]*(Σ w·y'[c] + y'[r]) + b   (y' carries dinv factor)
__global__ __launch_bounds__(256) void gather_k(const int* __restrict__ row_ptr,
                                                const float* __restrict__ dinv,
                                                const unsigned int* __restrict__ csr,
                                                const unsigned short* __restrict__ yp,
                                                const float* __restrict__ b,
                                                float* __restrict__ out) {
    int wv = threadIdx.x >> 6;
    int lane = threadIdx.x & 63;
    int n = blockIdx.x * 4 + wv;          // grid covers exactly 100000

    int s = row_ptr[n];
    int cnt = row_ptr[n + 1] - s;
    float acc = bf2f(yp[n * D + lane]);   // self-loop term

    for (int base = 0; base < cnt; base += 64) {
        int m = cnt - base; if (m > 64) m = 64;
        // one coalesced load fetches up to 64 records for this row
        unsigned int rec = (lane < m) ? csr[s + base + lane] : 0u;
        int r = 0;
        for (; r + 7 < m; r += 8) {
            unsigned int u[8];
#pragma unroll
            for (int q = 0; q < 8; ++q)
                u[q] = __builtin_amdgcn_readlane(rec, r + q);
            float yv[8];
#pragma unroll
            for (int q = 0; q < 8; ++q)
                yv[q] = bf2f(yp[(u[q] & 0x1FFFFu) * D + lane]);
#pragma unroll
            for (int q = 0; q < 8; ++q)
                acc += (float)(u[q] >> 17) * (1.0f / 32767.0f) * yv[q];
        }
        for (; r < m; ++r) {
            unsigned int u = __builtin_amdgcn_readlane(rec, r);
            acc += (float)(u >> 17) * (1.0f / 32767.0f)
                 * bf2f(yp[(u & 0x1FFFFu) * D + lane]);
        }
    }

    float o = dinv[n] * acc + b[lane];
    __builtin_nontemporal_store(o, &out[n * D + lane]);
}

// ---------------------------------------------------------------------------
extern "C" void kernel_launch(void* const* d_in, const int* in_sizes, int n_in,
                              void* d_out, int out_size, void* d_ws, size_t ws_size,
                              hipStream_t stream) {
    const float* x  = (const float*)d_in[0];
    const int*   ei = (const int*)d_in[1];     // [2, E]
    const float* ew = (const float*)d_in[2];
    const float* W  = (const float*)d_in[3];
    const float* b  = (const float*)d_in[4];
    float* out = (float*)d_out;

    char* ws = (char*)d_ws;
    int*                bin_cursor = (int*)                ws;               // 3.1 KB
    int*                bin_base   = (int*)               (ws + 4096);       // 3.1 KB
    int*                row_ptr    = (int*)               (ws + 16384);      // 400 KB
    float*              dinv       = (float*)             (ws + 524288);     // 400 KB
    unsigned short*     yp         = (unsigned short*)    (ws + 1048576);    // 12.8 MB
    unsigned int*       csr        = (unsigned int*)      (ws + 14155776);   // 6.4 MB
    unsigned long long* binbuf     = (unsigned long long*)(ws + 20971520);   // 16.0 MB (end ~37 MB)

    hipMemsetAsync(bin_cursor, 0, NBINS * sizeof(int), stream);
    passA_k <<<NCHUNK, 512, 0, stream>>>(ei, ew, bin_cursor, binbuf);
    base_k  <<<1, 256, 0, stream>>>(bin_cursor, bin_base, row_ptr);
    passB_k <<<NBINS, 256, 0, stream>>>(bin_cursor, bin_base, binbuf, csr, row_ptr, dinv);
    xw_k    <<<(N_NODES + 63) / 64, 256, 0, stream>>>(x, W, dinv, yp);
    gather_k<<<N_NODES / 4, 256, 0, stream>>>(row_ptr, dinv, csr, yp, b, out);
}